// Round 1
// baseline (1230.506 us; speedup 1.0000x reference)
//
#include <hip/hip_runtime.h>
#include <hip/hip_bf16.h>
#include <stdint.h>

typedef __attribute__((ext_vector_type(4))) float floatx4;
typedef __attribute__((ext_vector_type(8))) short short8;

#define DEVI __device__ __forceinline__

// Problem constants
constexpr int Bc   = 4;
constexpr int Sc   = 1024;
constexpr int Hc   = 4096;
constexpr int NHc  = 32;
constexpr int NKVc = 8;
constexpr int Dc   = 128;
constexpr int QKVO = 6144;           // NH*D + 2*NKV*D
constexpr int Mc   = Bc * Sc;        // 4096 tokens

DEVI unsigned short f2bf(float f) {
  union { float f; unsigned u; } x; x.f = f;
  unsigned u = x.u;
  u += 0x7fffu + ((u >> 16) & 1u);   // RNE
  return (unsigned short)(u >> 16);
}

DEVI short8 cvt8(floatx4 a, floatx4 b) {
  short8 r;
  r[0] = (short)f2bf(a[0]); r[1] = (short)f2bf(a[1]);
  r[2] = (short)f2bf(a[2]); r[3] = (short)f2bf(a[3]);
  r[4] = (short)f2bf(b[0]); r[5] = (short)f2bf(b[1]);
  r[6] = (short)f2bf(b[2]); r[7] = (short)f2bf(b[3]);
  return r;
}

// ---------------------------------------------------------------------------
// GEMM: C[M,N] = A[M,K] * B[K,N].  A is f32 or bf16(ushort); B is f32 weights.
// 128x128 tile, BK=32, 256 threads (4 waves in 2x2), 16x16x32 bf16 MFMA.
// LDS: As[row][k] and Bs[col][k], stride 40 bf16 (80B, 16B-aligned rows).
// ---------------------------------------------------------------------------
template<bool ABF16, bool OBF16>
__global__ __launch_bounds__(256)
void gemm_tile(const void* __restrict__ Ap, const float* __restrict__ Bw,
               void* __restrict__ Cp, int M, int N, int K)
{
  __shared__ __align__(16) unsigned short As[128 * 40];
  __shared__ __align__(16) unsigned short Bs[128 * 40];

  const int tid = threadIdx.x;
  const int nb  = N >> 7;
  const int bm  = blockIdx.x / nb, bn = blockIdx.x % nb;
  const int m0  = bm << 7, n0 = bn << 7;
  const int wid = tid >> 6, lane = tid & 63;
  const int wr  = (wid >> 1) << 6;     // wave row offset (0/64)
  const int wc  = (wid & 1) << 6;      // wave col offset (0/64)
  const int fr  = lane & 15;           // frag row/col
  const int kk  = (lane >> 4) << 3;    // frag k offset (0,8,16,24)

  const floatx4 fz = {0.f, 0.f, 0.f, 0.f};
  floatx4 acc[4][4];
#pragma unroll
  for (int i = 0; i < 4; ++i)
#pragma unroll
    for (int j = 0; j < 4; ++j) acc[i][j] = fz;

  // staging assignment
  const int arow = tid >> 1, ak0 = (tid & 1) << 4;      // A: 128 rows x 32 k
  const int bn0  = (tid & 15) << 3, bk0 = (tid >> 4) << 1; // B: 32 k x 128 n

  const int ktiles = K >> 5;
  for (int kt = 0; kt < ktiles; ++kt) {
    const int k0 = kt << 5;

    // ---- load A strip (16 elems) ----
    short8 a0, a1;
    if constexpr (ABF16) {
      const unsigned short* src =
          (const unsigned short*)Ap + (size_t)(m0 + arow) * K + k0 + ak0;
      a0 = *(const short8*)src;
      a1 = *(const short8*)(src + 8);
    } else {
      const float* src = (const float*)Ap + (size_t)(m0 + arow) * K + k0 + ak0;
      floatx4 f0 = *(const floatx4*)(src + 0);
      floatx4 f1 = *(const floatx4*)(src + 4);
      floatx4 f2 = *(const floatx4*)(src + 8);
      floatx4 f3 = *(const floatx4*)(src + 12);
      a0 = cvt8(f0, f1);
      a1 = cvt8(f2, f3);
    }

    // ---- load B strip: 2 k-rows x 8 n ----
    const float* bsrc0 = Bw + (size_t)(k0 + bk0) * N + n0 + bn0;
    const float* bsrc1 = bsrc0 + N;
    floatx4 r00 = *(const floatx4*)(bsrc0 + 0);
    floatx4 r01 = *(const floatx4*)(bsrc0 + 4);
    floatx4 r10 = *(const floatx4*)(bsrc1 + 0);
    floatx4 r11 = *(const floatx4*)(bsrc1 + 4);

    *(short8*)&As[arow * 40 + ak0]     = a0;
    *(short8*)&As[arow * 40 + ak0 + 8] = a1;

    unsigned pk[8];
#pragma unroll
    for (int j = 0; j < 4; ++j) {
      pk[j]     = (unsigned)f2bf(r00[j]) | ((unsigned)f2bf(r10[j]) << 16);
      pk[4 + j] = (unsigned)f2bf(r01[j]) | ((unsigned)f2bf(r11[j]) << 16);
    }
#pragma unroll
    for (int j = 0; j < 8; ++j)
      *(unsigned*)&Bs[(bn0 + j) * 40 + bk0] = pk[j];

    __syncthreads();

    short8 af[4], bf[4];
#pragma unroll
    for (int i = 0; i < 4; ++i)
      af[i] = *(const short8*)&As[(wr + i * 16 + fr) * 40 + kk];
#pragma unroll
    for (int j = 0; j < 4; ++j)
      bf[j] = *(const short8*)&Bs[(wc + j * 16 + fr) * 40 + kk];
#pragma unroll
    for (int i = 0; i < 4; ++i)
#pragma unroll
      for (int j = 0; j < 4; ++j)
        acc[i][j] = __builtin_amdgcn_mfma_f32_16x16x32_bf16(af[i], bf[j],
                                                            acc[i][j], 0, 0, 0);
    __syncthreads();
  }

  // epilogue: C row = (lane>>4)*4 + rr, col = lane&15 within each 16x16 frag
  const int r4 = (lane >> 4) << 2;
#pragma unroll
  for (int i = 0; i < 4; ++i) {
#pragma unroll
    for (int rr = 0; rr < 4; ++rr) {
      const size_t row = (size_t)(m0 + wr + i * 16 + r4 + rr);
#pragma unroll
      for (int j = 0; j < 4; ++j) {
        const size_t col = (size_t)(n0 + wc + j * 16 + fr);
        const float v = acc[i][j][rr];
        if constexpr (OBF16)
          ((unsigned short*)Cp)[row * N + col] = f2bf(v);
        else
          ((float*)Cp)[row * N + col] = v;
      }
    }
  }
}

// ---------------------------------------------------------------------------
// Flash attention with causal mask + ALiBi-sqrt bias.
// 1 wave per (batch, head, 16-row Q block). KBLK=32.
// qkv: bf16 [4096 tokens][6144]; attn out: bf16 [4096][4096].
// ---------------------------------------------------------------------------
__global__ __launch_bounds__(64)
void attn_fwd(const unsigned short* __restrict__ qkv,
              unsigned short* __restrict__ attn)
{
  __shared__ __align__(16) unsigned short Plds[16 * 40];

  const int bid  = blockIdx.x;
  const int qb   = bid & 63;          // q block (of 16 rows)
  const int h    = (bid >> 6) & 31;   // head
  const int b    = bid >> 11;         // batch
  const int lane = threadIdx.x;
  const int fr   = lane & 15;
  const int kk8  = (lane >> 4) << 3;
  const int q4   = (lane >> 4) << 2;
  const int hkv  = h >> 2;
  const float slope = exp2f(-0.25f * (float)(h + 1));
  const float scale = 0.08838834764831845f;   // 1/sqrt(128)

  const unsigned short* qp = qkv + (size_t)b * Sc * QKVO + (size_t)h * Dc;
  const unsigned short* kp = qkv + (size_t)b * Sc * QKVO + NHc * Dc + (size_t)hkv * Dc;
  const unsigned short* vp = qkv + (size_t)b * Sc * QKVO + NHc * Dc + NKVc * Dc + (size_t)hkv * Dc;

  // Q fragments (row = lane&15, k-slices of 32 over D=128)
  short8 qf[4];
  const int qrow = qb * 16 + fr;
#pragma unroll
  for (int s = 0; s < 4; ++s)
    qf[s] = *(const short8*)(qp + (size_t)qrow * QKVO + s * 32 + kk8);

  const floatx4 fz = {0.f, 0.f, 0.f, 0.f};
  floatx4 o[8];
#pragma unroll
  for (int j = 0; j < 8; ++j) o[j] = fz;
  float mrow[4] = {-1e30f, -1e30f, -1e30f, -1e30f};
  float lrow[4] = {0.f, 0.f, 0.f, 0.f};

  const int kbmax = (qb * 16 + 15) >> 5;
  for (int kb = 0; kb <= kbmax; ++kb) {
    // ---- S = Q K^T for 16q x 32k (two 16-col halves) ----
    floatx4 sc[2];
    sc[0] = fz; sc[1] = fz;
#pragma unroll
    for (int half = 0; half < 2; ++half) {
      const int kcol = kb * 32 + half * 16 + fr;
#pragma unroll
      for (int s = 0; s < 4; ++s) {
        short8 kf = *(const short8*)(kp + (size_t)kcol * QKVO + s * 32 + kk8);
        sc[half] = __builtin_amdgcn_mfma_f32_16x16x32_bf16(qf[s], kf, sc[half], 0, 0, 0);
      }
    }

    // ---- online softmax ----
    float p0v[4], p1v[4];
#pragma unroll
    for (int rr = 0; rr < 4; ++rr) {
      const int qg  = qb * 16 + q4 + rr;
      const int kg0 = kb * 32 + fr;
      const int kg1 = kb * 32 + 16 + fr;
      const float v0 = (kg0 <= qg)
          ? sc[0][rr] * scale - slope * sqrtf((float)(qg - kg0)) : -1e30f;
      const float v1 = (kg1 <= qg)
          ? sc[1][rr] * scale - slope * sqrtf((float)(qg - kg1)) : -1e30f;
      float pm = fmaxf(v0, v1);
#pragma unroll
      for (int m = 1; m < 16; m <<= 1) pm = fmaxf(pm, __shfl_xor(pm, m));
      const float mnew = fmaxf(mrow[rr], pm);
      const float corr = __expf(mrow[rr] - mnew);
      const float p0 = __expf(v0 - mnew);
      const float p1 = __expf(v1 - mnew);
      float rs = p0 + p1;
#pragma unroll
      for (int m = 1; m < 16; m <<= 1) rs += __shfl_xor(rs, m);
      lrow[rr] = lrow[rr] * corr + rs;
      mrow[rr] = mnew;
#pragma unroll
      for (int j = 0; j < 8; ++j) o[j][rr] *= corr;
      p0v[rr] = p0; p1v[rr] = p1;
    }

    // ---- transpose P through LDS (C-layout -> A-operand layout) ----
    __syncthreads();
#pragma unroll
    for (int rr = 0; rr < 4; ++rr) {
      Plds[(q4 + rr) * 40 + fr]      = f2bf(p0v[rr]);
      Plds[(q4 + rr) * 40 + 16 + fr] = f2bf(p1v[rr]);
    }
    __syncthreads();
    const short8 pa = *(const short8*)&Plds[fr * 40 + kk8];

    // ---- O += P V ----
#pragma unroll
    for (int j = 0; j < 8; ++j) {
      short8 vf;
#pragma unroll
      for (int t = 0; t < 8; ++t)
        vf[t] = (short)vp[(size_t)(kb * 32 + kk8 + t) * QKVO + j * 16 + fr];
      o[j] = __builtin_amdgcn_mfma_f32_16x16x32_bf16(pa, vf, o[j], 0, 0, 0);
    }
  }

  // ---- epilogue ----
#pragma unroll
  for (int rr = 0; rr < 4; ++rr) {
    const float inv = 1.f / lrow[rr];
    const size_t tok = (size_t)b * Sc + qb * 16 + q4 + rr;
#pragma unroll
    for (int j = 0; j < 8; ++j)
      attn[tok * (size_t)(NHc * Dc) + h * Dc + j * 16 + fr] = f2bf(o[rr >= 0 ? j : j][rr] * inv);
  }
}

// ---------------------------------------------------------------------------
extern "C" void kernel_launch(void* const* d_in, const int* in_sizes, int n_in,
                              void* d_out, int out_size, void* d_ws, size_t ws_size,
                              hipStream_t stream)
{
  const float* hidden = (const float*)d_in[0];
  const float* w_qkv  = (const float*)d_in[1];
  const float* w_o    = (const float*)d_in[2];
  float* out = (float*)d_out;

  unsigned short* qkvb  = (unsigned short*)d_ws;             // [4096][6144] bf16
  unsigned short* attnb = qkvb + (size_t)Mc * QKVO;          // [4096][4096] bf16

  // 1) qkv = hidden @ w_qkv   (M=4096, N=6144, K=4096)
  gemm_tile<false, true><<<dim3((Mc / 128) * (QKVO / 128)), dim3(256), 0, stream>>>(
      hidden, w_qkv, qkvb, Mc, QKVO, Hc);

  // 2) attention
  attn_fwd<<<dim3(Bc * NHc * (Sc / 16)), dim3(64), 0, stream>>>(qkvb, attnb);

  // 3) out = attn @ w_o       (M=4096, N=4096, K=4096)
  gemm_tile<true, false><<<dim3((Mc / 128) * (Hc / 128)), dim3(256), 0, stream>>>(
      attnb, w_o, out, Mc, Hc, NHc * Dc);
}

// Round 2
// 804.055 us; speedup vs baseline: 1.5304x; 1.5304x over previous
//
#include <hip/hip_runtime.h>
#include <stdint.h>

typedef __attribute__((ext_vector_type(4))) float floatx4;
typedef __attribute__((ext_vector_type(8))) short short8;
typedef unsigned short ushort_t;

#define DEVI __device__ __forceinline__

// Problem constants
constexpr int Bc   = 4;
constexpr int Sc   = 1024;
constexpr int Hc   = 4096;
constexpr int NHc  = 32;
constexpr int NKVc = 8;
constexpr int Dc   = 128;
constexpr int QKVO = 6144;           // NH*D + 2*NKV*D
constexpr int Mc   = Bc * Sc;        // 4096 tokens

DEVI ushort_t f2bf(float f) {
  union { float f; unsigned u; } x; x.f = f;
  unsigned u = x.u;
  u += 0x7fffu + ((u >> 16) & 1u);   // RNE
  return (ushort_t)(u >> 16);
}

DEVI short8 cvt8(floatx4 a, floatx4 b) {
  short8 r;
  r[0] = (short)f2bf(a[0]); r[1] = (short)f2bf(a[1]);
  r[2] = (short)f2bf(a[2]); r[3] = (short)f2bf(a[3]);
  r[4] = (short)f2bf(b[0]); r[5] = (short)f2bf(b[1]);
  r[6] = (short)f2bf(b[2]); r[7] = (short)f2bf(b[3]);
  return r;
}

DEVI void load_lds16(const ushort_t* g, ushort_t* l) {
  __builtin_amdgcn_global_load_lds(
      (const __attribute__((address_space(1))) void*)g,
      (__attribute__((address_space(3))) void*)l, 16, 0, 0);
}

// ---------------------------------------------------------------------------
// f32 -> bf16 plain convert (8 elems/thread)
// ---------------------------------------------------------------------------
__global__ __launch_bounds__(256)
void cvt_bf16(const float* __restrict__ src, ushort_t* __restrict__ dst, int n8)
{
  const int i = blockIdx.x * 256 + threadIdx.x;
  if (i >= n8) return;
  const floatx4 f0 = *(const floatx4*)(src + (size_t)i * 8);
  const floatx4 f1 = *(const floatx4*)(src + (size_t)i * 8 + 4);
  *(short8*)(dst + (size_t)i * 8) = cvt8(f0, f1);
}

// ---------------------------------------------------------------------------
// transpose + convert: src[R][C] f32 -> dst[C][R] bf16.  64x64 tiles.
// ---------------------------------------------------------------------------
__global__ __launch_bounds__(256)
void transpose_cvt(const float* __restrict__ src, ushort_t* __restrict__ dst,
                   int R, int C)
{
  __shared__ float ts[64][67];
  const int cb = C >> 6;
  const int r0 = (blockIdx.x / cb) << 6;
  const int c0 = (blockIdx.x % cb) << 6;
  const int t  = threadIdx.x;

  const int lr = t >> 4, lc = (t & 15) << 2;
#pragma unroll
  for (int i = 0; i < 4; ++i) {
    const floatx4 v = *(const floatx4*)(src + (size_t)(r0 + lr + 16 * i) * C + c0 + lc);
#pragma unroll
    for (int j = 0; j < 4; ++j) ts[lr + 16 * i][lc + j] = v[j];
  }
  __syncthreads();

  const int c     = ((t >> 6) << 4) + ((t & 63) >> 2);
  const int chunk = t & 3;
  short8 t0, t1;
#pragma unroll
  for (int k = 0; k < 8; ++k) t0[k] = (short)f2bf(ts[chunk * 16 + k][c]);
#pragma unroll
  for (int k = 0; k < 8; ++k) t1[k] = (short)f2bf(ts[chunk * 16 + 8 + k][c]);
  ushort_t* dp = dst + (size_t)(c0 + c) * R + r0 + chunk * 16;
  *(short8*)dp       = t0;
  *(short8*)(dp + 8) = t1;
}

// ---------------------------------------------------------------------------
// GEMM: C[M,N] = A[M,K] * BT[N,K]^T, all bf16 in, f32 or bf16 out.
// m97 structure: 128x128 tile, BK=64, 4 waves (2x2), global_load_lds w=16,
// both-sides XOR swizzle: storage_byte = logical_byte ^ ((row&7)<<4).
// ---------------------------------------------------------------------------
template<bool OBF16>
__global__ __launch_bounds__(256)
void gemm_nt(const ushort_t* __restrict__ A, const ushort_t* __restrict__ BT,
             void* __restrict__ Cp, int M, int N, int K)
{
  __shared__ __align__(16) ushort_t As[128 * 64];
  __shared__ __align__(16) ushort_t Bs[128 * 64];

  const int nb  = N >> 7;
  const int nwg = (M >> 7) * nb;
  int bid = blockIdx.x;
  bid = (bid & 7) * (nwg >> 3) + (bid >> 3);     // XCD swizzle (nwg%8==0)
  const int bm = bid / nb, bn = bid % nb;
  const int m0 = bm << 7, n0 = bn << 7;

  const int tid  = threadIdx.x;
  const int wid  = tid >> 6, lane = tid & 63;
  const int wr   = (wid >> 1) << 6, wc = (wid & 1) << 6;
  const int fr   = lane & 15;
  const int srow = lane >> 3;                          // 0..7
  const int scol = ((lane & 7) << 4) ^ (srow << 4);    // pre-swizzled src col byte
  const int rsw  = (fr & 7) << 4;                      // read-side XOR
  const int kb16 = (lane >> 4) << 4;                   // frag k byte offset

  const ushort_t* ag = A  + (size_t)(m0 + wid * 32 + srow) * K + (scol >> 1);
  const ushort_t* bg = BT + (size_t)(n0 + wid * 32 + srow) * K + (scol >> 1);
  ushort_t* as_u = &As[wid * 4 * 512];
  ushort_t* bs_u = &Bs[wid * 4 * 512];

  const floatx4 fz = {0.f, 0.f, 0.f, 0.f};
  floatx4 acc[4][4];
#pragma unroll
  for (int i = 0; i < 4; ++i)
#pragma unroll
    for (int j = 0; j < 4; ++j) acc[i][j] = fz;

  const char* Ab = (const char*)As + (size_t)(wr + fr) * 128;
  const char* Bb = (const char*)Bs + (size_t)(wc + fr) * 128;

  for (int k0 = 0; k0 < K; k0 += 64) {
#pragma unroll
    for (int i = 0; i < 4; ++i)
      load_lds16(ag + (size_t)i * 8 * K + k0, as_u + i * 512);
#pragma unroll
    for (int i = 0; i < 4; ++i)
      load_lds16(bg + (size_t)i * 8 * K + k0, bs_u + i * 512);
    __syncthreads();

#pragma unroll
    for (int ks = 0; ks < 2; ++ks) {
      const int co = (ks * 64 + kb16) ^ rsw;
      short8 af[4], bf[4];
#pragma unroll
      for (int i = 0; i < 4; ++i) af[i] = *(const short8*)(Ab + i * 2048 + co);
#pragma unroll
      for (int j = 0; j < 4; ++j) bf[j] = *(const short8*)(Bb + j * 2048 + co);
#pragma unroll
      for (int i = 0; i < 4; ++i)
#pragma unroll
        for (int j = 0; j < 4; ++j)
          acc[i][j] = __builtin_amdgcn_mfma_f32_16x16x32_bf16(af[i], bf[j],
                                                              acc[i][j], 0, 0, 0);
    }
    __syncthreads();
  }

  // epilogue: frag row = (lane>>4)*4 + rr, col = lane&15
  const int r4 = (lane >> 4) << 2;
#pragma unroll
  for (int i = 0; i < 4; ++i) {
#pragma unroll
    for (int rr = 0; rr < 4; ++rr) {
      const size_t row = (size_t)(m0 + wr + i * 16 + r4 + rr);
#pragma unroll
      for (int j = 0; j < 4; ++j) {
        const size_t col = (size_t)(n0 + wc + j * 16 + fr);
        if constexpr (OBF16)
          ((ushort_t*)Cp)[row * N + col] = f2bf(acc[i][j][rr]);
        else
          ((float*)Cp)[row * N + col] = acc[i][j][rr];
      }
    }
  }
}

// ---------------------------------------------------------------------------
// Flash attention with causal mask + ALiBi-sqrt bias (unchanged from R0).
// 1 wave per (batch, head, 16-row Q block). KBLK=32.
// ---------------------------------------------------------------------------
__global__ __launch_bounds__(64)
void attn_fwd(const ushort_t* __restrict__ qkv,
              ushort_t* __restrict__ attn)
{
  __shared__ __align__(16) ushort_t Plds[16 * 40];

  const int bid  = blockIdx.x;
  const int qb   = bid & 63;
  const int h    = (bid >> 6) & 31;
  const int b    = bid >> 11;
  const int lane = threadIdx.x;
  const int fr   = lane & 15;
  const int kk8  = (lane >> 4) << 3;
  const int q4   = (lane >> 4) << 2;
  const int hkv  = h >> 2;
  const float slope = exp2f(-0.25f * (float)(h + 1));
  const float scale = 0.08838834764831845f;

  const ushort_t* qp = qkv + (size_t)b * Sc * QKVO + (size_t)h * Dc;
  const ushort_t* kp = qkv + (size_t)b * Sc * QKVO + NHc * Dc + (size_t)hkv * Dc;
  const ushort_t* vp = qkv + (size_t)b * Sc * QKVO + NHc * Dc + NKVc * Dc + (size_t)hkv * Dc;

  short8 qf[4];
  const int qrow = qb * 16 + fr;
#pragma unroll
  for (int s = 0; s < 4; ++s)
    qf[s] = *(const short8*)(qp + (size_t)qrow * QKVO + s * 32 + kk8);

  const floatx4 fz = {0.f, 0.f, 0.f, 0.f};
  floatx4 o[8];
#pragma unroll
  for (int j = 0; j < 8; ++j) o[j] = fz;
  float mrow[4] = {-1e30f, -1e30f, -1e30f, -1e30f};
  float lrow[4] = {0.f, 0.f, 0.f, 0.f};

  const int kbmax = (qb * 16 + 15) >> 5;
  for (int kb = 0; kb <= kbmax; ++kb) {
    floatx4 sc[2];
    sc[0] = fz; sc[1] = fz;
#pragma unroll
    for (int half = 0; half < 2; ++half) {
      const int kcol = kb * 32 + half * 16 + fr;
#pragma unroll
      for (int s = 0; s < 4; ++s) {
        short8 kf = *(const short8*)(kp + (size_t)kcol * QKVO + s * 32 + kk8);
        sc[half] = __builtin_amdgcn_mfma_f32_16x16x32_bf16(qf[s], kf, sc[half], 0, 0, 0);
      }
    }

    float p0v[4], p1v[4];
#pragma unroll
    for (int rr = 0; rr < 4; ++rr) {
      const int qg  = qb * 16 + q4 + rr;
      const int kg0 = kb * 32 + fr;
      const int kg1 = kb * 32 + 16 + fr;
      const float v0 = (kg0 <= qg)
          ? sc[0][rr] * scale - slope * sqrtf((float)(qg - kg0)) : -1e30f;
      const float v1 = (kg1 <= qg)
          ? sc[1][rr] * scale - slope * sqrtf((float)(qg - kg1)) : -1e30f;
      float pm = fmaxf(v0, v1);
#pragma unroll
      for (int m = 1; m < 16; m <<= 1) pm = fmaxf(pm, __shfl_xor(pm, m));
      const float mnew = fmaxf(mrow[rr], pm);
      const float corr = __expf(mrow[rr] - mnew);
      const float p0 = __expf(v0 - mnew);
      const float p1 = __expf(v1 - mnew);
      float rs = p0 + p1;
#pragma unroll
      for (int m = 1; m < 16; m <<= 1) rs += __shfl_xor(rs, m);
      lrow[rr] = lrow[rr] * corr + rs;
      mrow[rr] = mnew;
#pragma unroll
      for (int j = 0; j < 8; ++j) o[j][rr] *= corr;
      p0v[rr] = p0; p1v[rr] = p1;
    }

    __syncthreads();
#pragma unroll
    for (int rr = 0; rr < 4; ++rr) {
      Plds[(q4 + rr) * 40 + fr]      = f2bf(p0v[rr]);
      Plds[(q4 + rr) * 40 + 16 + fr] = f2bf(p1v[rr]);
    }
    __syncthreads();
    const short8 pa = *(const short8*)&Plds[fr * 40 + kk8];

#pragma unroll
    for (int j = 0; j < 8; ++j) {
      short8 vf;
#pragma unroll
      for (int t = 0; t < 8; ++t)
        vf[t] = (short)vp[(size_t)(kb * 32 + kk8 + t) * QKVO + j * 16 + fr];
      o[j] = __builtin_amdgcn_mfma_f32_16x16x32_bf16(pa, vf, o[j], 0, 0, 0);
    }
  }

#pragma unroll
  for (int rr = 0; rr < 4; ++rr) {
    const float inv = 1.f / lrow[rr];
    const size_t tok = (size_t)b * Sc + qb * 16 + q4 + rr;
#pragma unroll
    for (int j = 0; j < 8; ++j)
      attn[tok * (size_t)(NHc * Dc) + h * Dc + j * 16 + fr] = f2bf(o[j][rr] * inv);
  }
}

// ---------------------------------------------------------------------------
extern "C" void kernel_launch(void* const* d_in, const int* in_sizes, int n_in,
                              void* d_out, int out_size, void* d_ws, size_t ws_size,
                              hipStream_t stream)
{
  const float* hidden = (const float*)d_in[0];
  const float* w_qkv  = (const float*)d_in[1];
  const float* w_o    = (const float*)d_in[2];
  float* out = (float*)d_out;

  // workspace layout (bf16 elems): total 134.2 MB
  ushort_t* wqT   = (ushort_t*)d_ws;                   // [6144][4096]  50.3MB
  ushort_t* hidb  = wqT + (size_t)QKVO * Hc;           // [4096][4096]  33.6MB
  ushort_t* qkvb  = hidb + (size_t)Mc * Hc;            // [4096][6144]  50.3MB
  ushort_t* attnb = hidb;                              // reuse after GEMM1
  ushort_t* woT   = wqT;                               // reuse after GEMM1

  // 1) hidden -> bf16
  cvt_bf16<<<dim3((Mc * Hc / 8) / 256), dim3(256), 0, stream>>>(
      hidden, hidb, Mc * Hc / 8);
  // 2) w_qkv^T -> bf16  [6144][4096]
  transpose_cvt<<<dim3((Hc / 64) * (QKVO / 64)), dim3(256), 0, stream>>>(
      w_qkv, wqT, Hc, QKVO);
  // 3) qkv = hidden @ w_qkv
  gemm_nt<true><<<dim3((Mc / 128) * (QKVO / 128)), dim3(256), 0, stream>>>(
      hidb, wqT, qkvb, Mc, QKVO, Hc);
  // 4) attention
  attn_fwd<<<dim3(Bc * NHc * (Sc / 16)), dim3(64), 0, stream>>>(qkvb, attnb);
  // 5) w_o^T -> bf16  [4096][4096]
  transpose_cvt<<<dim3((Hc / 64) * (Hc / 64)), dim3(256), 0, stream>>>(
      w_o, woT, Hc, Hc);
  // 6) out = attn @ w_o
  gemm_nt<false><<<dim3((Mc / 128) * (Hc / 128)), dim3(256), 0, stream>>>(
      attnb, woT, out, Mc, Hc, Hc);
}

// Round 4
// 795.106 us; speedup vs baseline: 1.5476x; 1.0113x over previous
//
#include <hip/hip_runtime.h>
#include <stdint.h>

typedef __attribute__((ext_vector_type(4))) float floatx4;
typedef __attribute__((ext_vector_type(8))) short short8;
typedef unsigned short ushort_t;

#define DEVI __device__ __forceinline__

// Problem constants
constexpr int Bc   = 4;
constexpr int Sc   = 1024;
constexpr int Hc   = 4096;
constexpr int NHc  = 32;
constexpr int NKVc = 8;
constexpr int Dc   = 128;
constexpr int QKVO = 6144;           // NH*D + 2*NKV*D
constexpr int Mc   = Bc * Sc;        // 4096 tokens

DEVI ushort_t f2bf(float f) {
  union { float f; unsigned u; } x; x.f = f;
  unsigned u = x.u;
  u += 0x7fffu + ((u >> 16) & 1u);   // RNE
  return (ushort_t)(u >> 16);
}

DEVI short8 cvt8(floatx4 a, floatx4 b) {
  short8 r;
  r[0] = (short)f2bf(a[0]); r[1] = (short)f2bf(a[1]);
  r[2] = (short)f2bf(a[2]); r[3] = (short)f2bf(a[3]);
  r[4] = (short)f2bf(b[0]); r[5] = (short)f2bf(b[1]);
  r[6] = (short)f2bf(b[2]); r[7] = (short)f2bf(b[3]);
  return r;
}

DEVI void load_lds16(const ushort_t* g, ushort_t* l) {
  __builtin_amdgcn_global_load_lds(
      (const __attribute__((address_space(1))) void*)g,
      (__attribute__((address_space(3))) void*)l, 16, 0, 0);
}

// ---------------------------------------------------------------------------
// f32 -> bf16 plain convert (8 elems/thread)
// ---------------------------------------------------------------------------
__global__ __launch_bounds__(256)
void cvt_bf16(const float* __restrict__ src, ushort_t* __restrict__ dst, int n8)
{
  const int i = blockIdx.x * 256 + threadIdx.x;
  if (i >= n8) return;
  const floatx4 f0 = *(const floatx4*)(src + (size_t)i * 8);
  const floatx4 f1 = *(const floatx4*)(src + (size_t)i * 8 + 4);
  *(short8*)(dst + (size_t)i * 8) = cvt8(f0, f1);
}

// ---------------------------------------------------------------------------
// transpose + convert: src[R][C] f32 -> dst[C][R] bf16.  64x64 tiles.
// ---------------------------------------------------------------------------
__global__ __launch_bounds__(256)
void transpose_cvt(const float* __restrict__ src, ushort_t* __restrict__ dst,
                   int R, int C)
{
  __shared__ float ts[64][67];
  const int cb = C >> 6;
  const int r0 = (blockIdx.x / cb) << 6;
  const int c0 = (blockIdx.x % cb) << 6;
  const int t  = threadIdx.x;

  const int lr = t >> 4, lc = (t & 15) << 2;
#pragma unroll
  for (int i = 0; i < 4; ++i) {
    const floatx4 v = *(const floatx4*)(src + (size_t)(r0 + lr + 16 * i) * C + c0 + lc);
#pragma unroll
    for (int j = 0; j < 4; ++j) ts[lr + 16 * i][lc + j] = v[j];
  }
  __syncthreads();

  const int c     = ((t >> 6) << 4) + ((t & 63) >> 2);
  const int chunk = t & 3;
  short8 t0, t1;
#pragma unroll
  for (int k = 0; k < 8; ++k) t0[k] = (short)f2bf(ts[chunk * 16 + k][c]);
#pragma unroll
  for (int k = 0; k < 8; ++k) t1[k] = (short)f2bf(ts[chunk * 16 + 8 + k][c]);
  ushort_t* dp = dst + (size_t)(c0 + c) * R + r0 + chunk * 16;
  *(short8*)dp       = t0;
  *(short8*)(dp + 8) = t1;
}

// ---------------------------------------------------------------------------
// V transpose (bf16 -> bf16): qkv[b][s][5120 + hkv*128 + d] -> vt[b][hkv][d][s]
// 64x64 tiles.  grid = 4b x 8hkv x 16sb x 2db = 1024 blocks.
// ---------------------------------------------------------------------------
__global__ __launch_bounds__(256)
void v_transpose(const ushort_t* __restrict__ qkv, ushort_t* __restrict__ vt)
{
  __shared__ ushort_t ts[64][72];
  const int bid = blockIdx.x;
  const int db  = bid & 1;
  const int sb  = (bid >> 1) & 15;
  const int hkv = (bid >> 5) & 7;
  const int b   = bid >> 8;
  const int t   = threadIdx.x;

  const ushort_t* src = qkv + (size_t)(b * Sc + sb * 64) * QKVO
                        + (NHc * Dc + NKVc * Dc) + hkv * Dc + db * 64;
  const int lr = t >> 3, lc = (t & 7) * 8;
  *(short8*)&ts[lr][lc]      = *(const short8*)(src + (size_t)lr * QKVO + lc);
  *(short8*)&ts[lr + 32][lc] = *(const short8*)(src + (size_t)(lr + 32) * QKVO + lc);
  __syncthreads();

  ushort_t* dst = vt + ((size_t)(b * NKVc + hkv) * Dc + db * 64) * Sc + sb * 64;
  const int dr  = t >> 2;
  const int sc0 = (t & 3) * 16;
  short8 o0, o1;
#pragma unroll
  for (int k = 0; k < 8; ++k) o0[k] = (short)ts[sc0 + k][dr];
#pragma unroll
  for (int k = 0; k < 8; ++k) o1[k] = (short)ts[sc0 + 8 + k][dr];
  *(short8*)(dst + (size_t)dr * Sc + sc0)     = o0;
  *(short8*)(dst + (size_t)dr * Sc + sc0 + 8) = o1;
}

// ---------------------------------------------------------------------------
// GEMM: C[M,N] = A[M,K] * BT[N,K]^T, all bf16 in, f32 or bf16 out.
// m97 structure: 128x128 tile, BK=64, 4 waves (2x2), global_load_lds w=16,
// both-sides XOR swizzle: storage_byte = logical_byte ^ ((row&7)<<4).
// ---------------------------------------------------------------------------
template<bool OBF16>
__global__ __launch_bounds__(256)
void gemm_nt(const ushort_t* __restrict__ A, const ushort_t* __restrict__ BT,
             void* __restrict__ Cp, int M, int N, int K)
{
  __shared__ __align__(16) ushort_t As[128 * 64];
  __shared__ __align__(16) ushort_t Bs[128 * 64];

  const int nb  = N >> 7;
  const int nwg = (M >> 7) * nb;
  int bid = blockIdx.x;
  bid = (bid & 7) * (nwg >> 3) + (bid >> 3);     // XCD swizzle (nwg%8==0)
  const int bm = bid / nb, bn = bid % nb;
  const int m0 = bm << 7, n0 = bn << 7;

  const int tid  = threadIdx.x;
  const int wid  = tid >> 6, lane = tid & 63;
  const int wr   = (wid >> 1) << 6, wc = (wid & 1) << 6;
  const int fr   = lane & 15;
  const int srow = lane >> 3;                          // 0..7
  const int scol = ((lane & 7) << 4) ^ (srow << 4);    // pre-swizzled src col byte
  const int rsw  = (fr & 7) << 4;                      // read-side XOR
  const int kb16 = (lane >> 4) << 4;                   // frag k byte offset

  const ushort_t* ag = A  + (size_t)(m0 + wid * 32 + srow) * K + (scol >> 1);
  const ushort_t* bg = BT + (size_t)(n0 + wid * 32 + srow) * K + (scol >> 1);
  ushort_t* as_u = &As[wid * 4 * 512];
  ushort_t* bs_u = &Bs[wid * 4 * 512];

  const floatx4 fz = {0.f, 0.f, 0.f, 0.f};
  floatx4 acc[4][4];
#pragma unroll
  for (int i = 0; i < 4; ++i)
#pragma unroll
    for (int j = 0; j < 4; ++j) acc[i][j] = fz;

  const char* Ab = (const char*)As + (size_t)(wr + fr) * 128;
  const char* Bb = (const char*)Bs + (size_t)(wc + fr) * 128;

  for (int k0 = 0; k0 < K; k0 += 64) {
#pragma unroll
    for (int i = 0; i < 4; ++i)
      load_lds16(ag + (size_t)i * 8 * K + k0, as_u + i * 512);
#pragma unroll
    for (int i = 0; i < 4; ++i)
      load_lds16(bg + (size_t)i * 8 * K + k0, bs_u + i * 512);
    __syncthreads();

#pragma unroll
    for (int ks = 0; ks < 2; ++ks) {
      const int co = (ks * 64 + kb16) ^ rsw;
      short8 af[4], bf[4];
#pragma unroll
      for (int i = 0; i < 4; ++i) af[i] = *(const short8*)(Ab + i * 2048 + co);
#pragma unroll
      for (int j = 0; j < 4; ++j) bf[j] = *(const short8*)(Bb + j * 2048 + co);
#pragma unroll
      for (int i = 0; i < 4; ++i)
#pragma unroll
        for (int j = 0; j < 4; ++j)
          acc[i][j] = __builtin_amdgcn_mfma_f32_16x16x32_bf16(af[i], bf[j],
                                                              acc[i][j], 0, 0, 0);
    }
    __syncthreads();
  }

  const int r4 = (lane >> 4) << 2;
#pragma unroll
  for (int i = 0; i < 4; ++i) {
#pragma unroll
    for (int rr = 0; rr < 4; ++rr) {
      const size_t row = (size_t)(m0 + wr + i * 16 + r4 + rr);
#pragma unroll
      for (int j = 0; j < 4; ++j) {
        const size_t col = (size_t)(n0 + wc + j * 16 + fr);
        if constexpr (OBF16)
          ((ushort_t*)Cp)[row * N + col] = f2bf(acc[i][j][rr]);
        else
          ((float*)Cp)[row * N + col] = acc[i][j][rr];
      }
    }
  }
}

// ---------------------------------------------------------------------------
// Flash attention, causal + ALiBi-sqrt.  1 wave per (b, head, 32 q rows).
// 2 16-row q fragments per wave; KBLK=32; V read from pre-transposed VT.
// Per-lane partial l-sum (reduced in epilogue); defer-max THR=8.
// ---------------------------------------------------------------------------
__global__ __launch_bounds__(64)
void attn_fwd(const ushort_t* __restrict__ qkv,
              const ushort_t* __restrict__ vt,
              ushort_t* __restrict__ attn)
{
  __shared__ __align__(16) ushort_t Plds[32 * 40];

  const int bid  = blockIdx.x;
  const int qb   = 31 - (bid & 31);     // heavy blocks first
  const int h    = (bid >> 5) & 31;
  const int b    = bid >> 10;
  const int lane = threadIdx.x;
  const int fr   = lane & 15;
  const int kk8  = (lane >> 4) << 3;
  const int q4   = (lane >> 4) << 2;
  const int hkv  = h >> 2;
  const float slope = exp2f(-0.25f * (float)(h + 1));
  const float scale = 0.08838834764831845f;   // 1/sqrt(128)

  const ushort_t* qp  = qkv + (size_t)b * Sc * QKVO + (size_t)h * Dc;
  const ushort_t* kp  = qkv + (size_t)b * Sc * QKVO + NHc * Dc + (size_t)hkv * Dc;
  const ushort_t* vtp = vt + (size_t)(b * NKVc + hkv) * Dc * Sc;

  short8 qf[2][4];
#pragma unroll
  for (int t = 0; t < 2; ++t) {
    const int qrow = qb * 32 + t * 16 + fr;
#pragma unroll
    for (int s = 0; s < 4; ++s)
      qf[t][s] = *(const short8*)(qp + (size_t)qrow * QKVO + s * 32 + kk8);
  }

  const floatx4 fz = {0.f, 0.f, 0.f, 0.f};
  floatx4 o[2][8];
#pragma unroll
  for (int t = 0; t < 2; ++t)
#pragma unroll
    for (int j = 0; j < 8; ++j) o[t][j] = fz;
  float mrow[2][4], lrow[2][4];
#pragma unroll
  for (int t = 0; t < 2; ++t)
#pragma unroll
    for (int rr = 0; rr < 4; ++rr) { mrow[t][rr] = -1e30f; lrow[t][rr] = 0.f; }

  for (int kb = 0; kb <= qb; ++kb) {
    // ---- S = Q K^T: 32q x 32k ----
    floatx4 s_[2][2];
    s_[0][0] = fz; s_[0][1] = fz; s_[1][0] = fz; s_[1][1] = fz;
#pragma unroll
    for (int half = 0; half < 2; ++half) {
      const int kcol = kb * 32 + half * 16 + fr;
#pragma unroll
      for (int s = 0; s < 4; ++s) {
        const short8 kf = *(const short8*)(kp + (size_t)kcol * QKVO + s * 32 + kk8);
        s_[0][half] = __builtin_amdgcn_mfma_f32_16x16x32_bf16(qf[0][s], kf, s_[0][half], 0, 0, 0);
        s_[1][half] = __builtin_amdgcn_mfma_f32_16x16x32_bf16(qf[1][s], kf, s_[1][half], 0, 0, 0);
      }
    }

    // ---- bias + causal mask (in place) ----
#pragma unroll
    for (int t = 0; t < 2; ++t)
#pragma unroll
      for (int rr = 0; rr < 4; ++rr) {
        const int qg  = qb * 32 + t * 16 + q4 + rr;
        const int dk0 = qg - (kb * 32 + fr);
        const int dk1 = dk0 - 16;
        s_[t][0][rr] = (dk0 >= 0)
            ? s_[t][0][rr] * scale - slope * sqrtf((float)dk0) : -1e30f;
        s_[t][1][rr] = (dk1 >= 0)
            ? s_[t][1][rr] * scale - slope * sqrtf((float)dk1) : -1e30f;
      }

    // ---- row max ----
    float pmv[2][4];
#pragma unroll
    for (int t = 0; t < 2; ++t)
#pragma unroll
      for (int rr = 0; rr < 4; ++rr) {
        float pm = fmaxf(s_[t][0][rr], s_[t][1][rr]);
#pragma unroll
        for (int m = 1; m < 16; m <<= 1) pm = fmaxf(pm, __shfl_xor(pm, m));
        pmv[t][rr] = pm;
      }

    // ---- defer-max rescale (T13) ----
    int need = 0;
#pragma unroll
    for (int t = 0; t < 2; ++t)
#pragma unroll
      for (int rr = 0; rr < 4; ++rr)
        need |= (pmv[t][rr] > mrow[t][rr] + 8.f) ? 1 : 0;
    if (__any(need)) {
#pragma unroll
      for (int t = 0; t < 2; ++t)
#pragma unroll
        for (int rr = 0; rr < 4; ++rr) {
          const float mnew = fmaxf(mrow[t][rr], pmv[t][rr]);
          const float corr = __expf(mrow[t][rr] - mnew);
          lrow[t][rr] *= corr;
          mrow[t][rr] = mnew;
#pragma unroll
          for (int j = 0; j < 8; ++j) o[t][j][rr] *= corr;
        }
    }

    // ---- P = exp(S - m), partial sums, transpose through LDS ----
    __syncthreads();
#pragma unroll
    for (int t = 0; t < 2; ++t)
#pragma unroll
      for (int rr = 0; rr < 4; ++rr) {
        const float p0 = __expf(s_[t][0][rr] - mrow[t][rr]);
        const float p1 = __expf(s_[t][1][rr] - mrow[t][rr]);
        lrow[t][rr] += p0 + p1;
        Plds[(t * 16 + q4 + rr) * 40 + fr]      = f2bf(p0);
        Plds[(t * 16 + q4 + rr) * 40 + 16 + fr] = f2bf(p1);
      }
    __syncthreads();
    short8 pa[2];
    pa[0] = *(const short8*)&Plds[fr * 40 + kk8];
    pa[1] = *(const short8*)&Plds[(16 + fr) * 40 + kk8];

    // ---- O += P V  (V from VT, contiguous loads) ----
#pragma unroll
    for (int j = 0; j < 8; ++j) {
      const short8 vf = *(const short8*)(vtp + (size_t)(j * 16 + fr) * Sc + kb * 32 + kk8);
      o[0][j] = __builtin_amdgcn_mfma_f32_16x16x32_bf16(pa[0], vf, o[0][j], 0, 0, 0);
      o[1][j] = __builtin_amdgcn_mfma_f32_16x16x32_bf16(pa[1], vf, o[1][j], 0, 0, 0);
    }
  }

  // ---- epilogue: reduce l across the 16-lane row group, normalize, store ----
#pragma unroll
  for (int t = 0; t < 2; ++t)
#pragma unroll
    for (int rr = 0; rr < 4; ++rr) {
      float rs = lrow[t][rr];
#pragma unroll
      for (int m = 1; m < 16; m <<= 1) rs += __shfl_xor(rs, m);
      const float inv = 1.f / rs;
      const size_t tok = (size_t)b * Sc + qb * 32 + t * 16 + q4 + rr;
#pragma unroll
      for (int j = 0; j < 8; ++j)
        attn[tok * (size_t)(NHc * Dc) + h * Dc + j * 16 + fr] = f2bf(o[t][j][rr] * inv);
    }
}

// ---------------------------------------------------------------------------
extern "C" void kernel_launch(void* const* d_in, const int* in_sizes, int n_in,
                              void* d_out, int out_size, void* d_ws, size_t ws_size,
                              hipStream_t stream)
{
  const float* hidden = (const float*)d_in[0];
  const float* w_qkv  = (const float*)d_in[1];
  const float* w_o    = (const float*)d_in[2];
  float* out = (float*)d_out;

  // workspace layout (bf16 elems): 134.2 MB total
  ushort_t* wqT   = (ushort_t*)d_ws;                   // [6144][4096]  50.3MB
  ushort_t* hidb  = wqT + (size_t)QKVO * Hc;           // [4096][4096]  33.6MB
  ushort_t* qkvb  = hidb + (size_t)Mc * Hc;            // [4096][6144]  50.3MB
  ushort_t* attnb = hidb;                              // reuse after GEMM1
  ushort_t* woT   = wqT;                               // reuse after GEMM1
  ushort_t* vtb   = wqT + (size_t)Mc * Hc;             // reuse: wqT+33.6MB, 8.4MB

  // 1) hidden -> bf16
  cvt_bf16<<<dim3((Mc * Hc / 8) / 256), dim3(256), 0, stream>>>(
      hidden, hidb, Mc * Hc / 8);
  // 2) w_qkv^T -> bf16  [6144][4096]
  transpose_cvt<<<dim3((Hc / 64) * (QKVO / 64)), dim3(256), 0, stream>>>(
      w_qkv, wqT, Hc, QKVO);
  // 3) qkv = hidden @ w_qkv
  gemm_nt<true><<<dim3((Mc / 128) * (QKVO / 128)), dim3(256), 0, stream>>>(
      hidb, wqT, qkvb, Mc, QKVO, Hc);
  // 4) V -> VT  [b][hkv][d][s]
  v_transpose<<<dim3(1024), dim3(256), 0, stream>>>(qkvb, vtb);
  // 5) attention
  attn_fwd<<<dim3(Bc * NHc * (Sc / 32)), dim3(64), 0, stream>>>(qkvb, vtb, attnb);
  // 6) w_o^T -> bf16  [4096][4096]
  transpose_cvt<<<dim3((Hc / 64) * (Hc / 64)), dim3(256), 0, stream>>>(
      w_o, woT, Hc, Hc);
  // 7) out = attn @ w_o
  gemm_nt<false><<<dim3((Mc / 128) * (Hc / 128)), dim3(256), 0, stream>>>(
      attnb, woT, out, Mc, Hc, Hc);
}

// Round 5
// 642.590 us; speedup vs baseline: 1.9149x; 1.2373x over previous
//
#include <hip/hip_runtime.h>
#include <stdint.h>

typedef __attribute__((ext_vector_type(4))) float floatx4;
typedef __attribute__((ext_vector_type(8))) short short8;
typedef unsigned short ushort_t;

#define DEVI __device__ __forceinline__

// Problem constants
constexpr int Bc   = 4;
constexpr int Sc   = 1024;
constexpr int Hc   = 4096;
constexpr int NHc  = 32;
constexpr int NKVc = 8;
constexpr int Dc   = 128;
constexpr int QKVO = 6144;           // NH*D + 2*NKV*D
constexpr int Mc   = Bc * Sc;        // 4096 tokens

DEVI ushort_t f2bf(float f) {
  union { float f; unsigned u; } x; x.f = f;
  unsigned u = x.u;
  u += 0x7fffu + ((u >> 16) & 1u);   // RNE
  return (ushort_t)(u >> 16);
}

DEVI short8 cvt8(floatx4 a, floatx4 b) {
  short8 r;
  r[0] = (short)f2bf(a[0]); r[1] = (short)f2bf(a[1]);
  r[2] = (short)f2bf(a[2]); r[3] = (short)f2bf(a[3]);
  r[4] = (short)f2bf(b[0]); r[5] = (short)f2bf(b[1]);
  r[6] = (short)f2bf(b[2]); r[7] = (short)f2bf(b[3]);
  return r;
}

DEVI void load_lds16(const ushort_t* g, ushort_t* l) {
  __builtin_amdgcn_global_load_lds(
      (const __attribute__((address_space(1))) void*)g,
      (__attribute__((address_space(3))) void*)l, 16, 0, 0);
}

// ---------------------------------------------------------------------------
// f32 -> bf16 plain convert (8 elems/thread)
// ---------------------------------------------------------------------------
__global__ __launch_bounds__(256)
void cvt_bf16(const float* __restrict__ src, ushort_t* __restrict__ dst, int n8)
{
  const int i = blockIdx.x * 256 + threadIdx.x;
  if (i >= n8) return;
  const floatx4 f0 = *(const floatx4*)(src + (size_t)i * 8);
  const floatx4 f1 = *(const floatx4*)(src + (size_t)i * 8 + 4);
  *(short8*)(dst + (size_t)i * 8) = cvt8(f0, f1);
}

// ---------------------------------------------------------------------------
// transpose + convert: src[R][C] f32 -> dst[C][R] bf16.  64x64 tiles.
// ---------------------------------------------------------------------------
__global__ __launch_bounds__(256)
void transpose_cvt(const float* __restrict__ src, ushort_t* __restrict__ dst,
                   int R, int C)
{
  __shared__ float ts[64][67];
  const int cb = C >> 6;
  const int r0 = (blockIdx.x / cb) << 6;
  const int c0 = (blockIdx.x % cb) << 6;
  const int t  = threadIdx.x;

  const int lr = t >> 4, lc = (t & 15) << 2;
#pragma unroll
  for (int i = 0; i < 4; ++i) {
    const floatx4 v = *(const floatx4*)(src + (size_t)(r0 + lr + 16 * i) * C + c0 + lc);
#pragma unroll
    for (int j = 0; j < 4; ++j) ts[lr + 16 * i][lc + j] = v[j];
  }
  __syncthreads();

  const int c     = ((t >> 6) << 4) + ((t & 63) >> 2);
  const int chunk = t & 3;
  short8 t0, t1;
#pragma unroll
  for (int k = 0; k < 8; ++k) t0[k] = (short)f2bf(ts[chunk * 16 + k][c]);
#pragma unroll
  for (int k = 0; k < 8; ++k) t1[k] = (short)f2bf(ts[chunk * 16 + 8 + k][c]);
  ushort_t* dp = dst + (size_t)(c0 + c) * R + r0 + chunk * 16;
  *(short8*)dp       = t0;
  *(short8*)(dp + 8) = t1;
}

// ---------------------------------------------------------------------------
// V transpose (bf16 -> bf16): qkv[b][s][5120 + hkv*128 + d] -> vt[b][hkv][d][s]
// ---------------------------------------------------------------------------
__global__ __launch_bounds__(256)
void v_transpose(const ushort_t* __restrict__ qkv, ushort_t* __restrict__ vt)
{
  __shared__ ushort_t ts[64][72];
  const int bid = blockIdx.x;
  const int db  = bid & 1;
  const int sb  = (bid >> 1) & 15;
  const int hkv = (bid >> 5) & 7;
  const int b   = bid >> 8;
  const int t   = threadIdx.x;

  const ushort_t* src = qkv + (size_t)(b * Sc + sb * 64) * QKVO
                        + (NHc * Dc + NKVc * Dc) + hkv * Dc + db * 64;
  const int lr = t >> 3, lc = (t & 7) * 8;
  *(short8*)&ts[lr][lc]      = *(const short8*)(src + (size_t)lr * QKVO + lc);
  *(short8*)&ts[lr + 32][lc] = *(const short8*)(src + (size_t)(lr + 32) * QKVO + lc);
  __syncthreads();

  ushort_t* dst = vt + ((size_t)(b * NKVc + hkv) * Dc + db * 64) * Sc + sb * 64;
  const int dr  = t >> 2;
  const int sc0 = (t & 3) * 16;
  short8 o0, o1;
#pragma unroll
  for (int k = 0; k < 8; ++k) o0[k] = (short)ts[sc0 + k][dr];
#pragma unroll
  for (int k = 0; k < 8; ++k) o1[k] = (short)ts[sc0 + 8 + k][dr];
  *(short8*)(dst + (size_t)dr * Sc + sc0)     = o0;
  *(short8*)(dst + (size_t)dr * Sc + sc0 + 8) = o1;
}

// ---------------------------------------------------------------------------
// GEMM: C[M,N] = A[M,K] * BT[N,K]^T, all bf16 in, f32 or bf16 out.
// m97 structure: 128x128 tile, BK=64, 4 waves (2x2), global_load_lds w=16,
// both-sides XOR swizzle: storage_byte = logical_byte ^ ((row&7)<<4).
// ---------------------------------------------------------------------------
template<bool OBF16>
__global__ __launch_bounds__(256)
void gemm_nt(const ushort_t* __restrict__ A, const ushort_t* __restrict__ BT,
             void* __restrict__ Cp, int M, int N, int K)
{
  __shared__ __align__(16) ushort_t As[128 * 64];
  __shared__ __align__(16) ushort_t Bs[128 * 64];

  const int nb  = N >> 7;
  const int nwg = (M >> 7) * nb;
  int bid = blockIdx.x;
  bid = (bid & 7) * (nwg >> 3) + (bid >> 3);     // XCD swizzle (nwg%8==0)
  const int bm = bid / nb, bn = bid % nb;
  const int m0 = bm << 7, n0 = bn << 7;

  const int tid  = threadIdx.x;
  const int wid  = tid >> 6, lane = tid & 63;
  const int wr   = (wid >> 1) << 6, wc = (wid & 1) << 6;
  const int fr   = lane & 15;
  const int srow = lane >> 3;                          // 0..7
  const int scol = ((lane & 7) << 4) ^ (srow << 4);    // pre-swizzled src col byte
  const int rsw  = (fr & 7) << 4;                      // read-side XOR
  const int kb16 = (lane >> 4) << 4;                   // frag k byte offset

  const ushort_t* ag = A  + (size_t)(m0 + wid * 32 + srow) * K + (scol >> 1);
  const ushort_t* bg = BT + (size_t)(n0 + wid * 32 + srow) * K + (scol >> 1);
  ushort_t* as_u = &As[wid * 4 * 512];
  ushort_t* bs_u = &Bs[wid * 4 * 512];

  const floatx4 fz = {0.f, 0.f, 0.f, 0.f};
  floatx4 acc[4][4];
#pragma unroll
  for (int i = 0; i < 4; ++i)
#pragma unroll
    for (int j = 0; j < 4; ++j) acc[i][j] = fz;

  const char* Ab = (const char*)As + (size_t)(wr + fr) * 128;
  const char* Bb = (const char*)Bs + (size_t)(wc + fr) * 128;

  for (int k0 = 0; k0 < K; k0 += 64) {
#pragma unroll
    for (int i = 0; i < 4; ++i)
      load_lds16(ag + (size_t)i * 8 * K + k0, as_u + i * 512);
#pragma unroll
    for (int i = 0; i < 4; ++i)
      load_lds16(bg + (size_t)i * 8 * K + k0, bs_u + i * 512);
    __syncthreads();

#pragma unroll
    for (int ks = 0; ks < 2; ++ks) {
      const int co = (ks * 64 + kb16) ^ rsw;
      short8 af[4], bf[4];
#pragma unroll
      for (int i = 0; i < 4; ++i) af[i] = *(const short8*)(Ab + i * 2048 + co);
#pragma unroll
      for (int j = 0; j < 4; ++j) bf[j] = *(const short8*)(Bb + j * 2048 + co);
#pragma unroll
      for (int i = 0; i < 4; ++i)
#pragma unroll
        for (int j = 0; j < 4; ++j)
          acc[i][j] = __builtin_amdgcn_mfma_f32_16x16x32_bf16(af[i], bf[j],
                                                              acc[i][j], 0, 0, 0);
    }
    __syncthreads();
  }

  const int r4 = (lane >> 4) << 2;
#pragma unroll
  for (int i = 0; i < 4; ++i) {
#pragma unroll
    for (int rr = 0; rr < 4; ++rr) {
      const size_t row = (size_t)(m0 + wr + i * 16 + r4 + rr);
#pragma unroll
      for (int j = 0; j < 4; ++j) {
        const size_t col = (size_t)(n0 + wc + j * 16 + fr);
        if constexpr (OBF16)
          ((ushort_t*)Cp)[row * N + col] = f2bf(acc[i][j][rr]);
        else
          ((float*)Cp)[row * N + col] = acc[i][j][rr];
      }
    }
  }
}

// ---------------------------------------------------------------------------
// Flash attention, causal + ALiBi-sqrt.
// Block = 256 thr = 4 waves = the 4 GQA heads of one kv head (shared K/V).
// Wave processes q-blocks (31-j) then (j): uniform 33 kb-iters for all waves.
// Grid mapped so all 16 blocks of a (b,hkv) group share one XCD's L2.
// Per-wave Plds slice -> NO barriers.  V prefetched before softmax.
// ---------------------------------------------------------------------------
__global__ __launch_bounds__(256, 2)
void attn_fwd(const ushort_t* __restrict__ qkv,
              const ushort_t* __restrict__ vt,
              ushort_t* __restrict__ attn)
{
  __shared__ __align__(16) ushort_t Plds[4][32 * 40];

  const int bid = blockIdx.x;          // 512 blocks
  const int x   = bid & 7;             // XCD slot
  const int p   = bid >> 3;            // 0..63
  const int j   = p & 15;              // pair index
  const int g   = ((p >> 4) << 3) + x; // (b,hkv) group 0..31, fixed per XCD slot
  const int b   = g >> 3;
  const int hkv = g & 7;

  const int tid  = threadIdx.x;
  const int wid  = tid >> 6, lane = tid & 63;
  const int h    = hkv * 4 + wid;      // this wave's q-head
  const int fr   = lane & 15;
  const int kk8  = (lane >> 4) << 3;
  const int q4   = (lane >> 4) << 2;
  const float slope = exp2f(-0.25f * (float)(h + 1));
  const float scale = 0.08838834764831845f;   // 1/sqrt(128)

  const ushort_t* qp  = qkv + (size_t)b * Sc * QKVO + (size_t)h * Dc;
  const ushort_t* kp  = qkv + (size_t)b * Sc * QKVO + NHc * Dc + (size_t)hkv * Dc;
  const ushort_t* vtp = vt + (size_t)(b * NKVc + hkv) * Dc * Sc;
  ushort_t* myP = &Plds[wid][0];

  const floatx4 fz = {0.f, 0.f, 0.f, 0.f};

  auto process = [&](const int qb) {
    short8 qf[2][4];
#pragma unroll
    for (int t = 0; t < 2; ++t) {
      const int qrow = qb * 32 + t * 16 + fr;
#pragma unroll
      for (int s = 0; s < 4; ++s)
        qf[t][s] = *(const short8*)(qp + (size_t)qrow * QKVO + s * 32 + kk8);
    }

    floatx4 o[2][8];
#pragma unroll
    for (int t = 0; t < 2; ++t)
#pragma unroll
      for (int jj = 0; jj < 8; ++jj) o[t][jj] = fz;
    float mrow[2][4], lrow[2][4];
#pragma unroll
    for (int t = 0; t < 2; ++t)
#pragma unroll
      for (int rr = 0; rr < 4; ++rr) { mrow[t][rr] = -1e30f; lrow[t][rr] = 0.f; }

    for (int kb = 0; kb <= qb; ++kb) {
      // ---- S = Q K^T: 32q x 32k ----
      floatx4 s_[2][2];
      s_[0][0] = fz; s_[0][1] = fz; s_[1][0] = fz; s_[1][1] = fz;
#pragma unroll
      for (int half = 0; half < 2; ++half) {
        const int kcol = kb * 32 + half * 16 + fr;
#pragma unroll
        for (int s = 0; s < 4; ++s) {
          const short8 kf = *(const short8*)(kp + (size_t)kcol * QKVO + s * 32 + kk8);
          s_[0][half] = __builtin_amdgcn_mfma_f32_16x16x32_bf16(qf[0][s], kf, s_[0][half], 0, 0, 0);
          s_[1][half] = __builtin_amdgcn_mfma_f32_16x16x32_bf16(qf[1][s], kf, s_[1][half], 0, 0, 0);
        }
      }

      // ---- V prefetch (independent of softmax; hides under VALU chain) ----
      short8 vf[8];
#pragma unroll
      for (int jj = 0; jj < 8; ++jj)
        vf[jj] = *(const short8*)(vtp + (size_t)(jj * 16 + fr) * Sc + kb * 32 + kk8);

      // ---- bias + causal mask ----
#pragma unroll
      for (int t = 0; t < 2; ++t)
#pragma unroll
        for (int rr = 0; rr < 4; ++rr) {
          const int qg  = qb * 32 + t * 16 + q4 + rr;
          const int dk0 = qg - (kb * 32 + fr);
          const int dk1 = dk0 - 16;
          s_[t][0][rr] = (dk0 >= 0)
              ? s_[t][0][rr] * scale - slope * sqrtf((float)dk0) : -1e30f;
          s_[t][1][rr] = (dk1 >= 0)
              ? s_[t][1][rr] * scale - slope * sqrtf((float)dk1) : -1e30f;
        }

      // ---- row max ----
      float pmv[2][4];
#pragma unroll
      for (int t = 0; t < 2; ++t)
#pragma unroll
        for (int rr = 0; rr < 4; ++rr) {
          float pm = fmaxf(s_[t][0][rr], s_[t][1][rr]);
#pragma unroll
          for (int m = 1; m < 16; m <<= 1) pm = fmaxf(pm, __shfl_xor(pm, m));
          pmv[t][rr] = pm;
        }

      // ---- defer-max rescale (T13) ----
      int need = 0;
#pragma unroll
      for (int t = 0; t < 2; ++t)
#pragma unroll
        for (int rr = 0; rr < 4; ++rr)
          need |= (pmv[t][rr] > mrow[t][rr] + 8.f) ? 1 : 0;
      if (__any(need)) {
#pragma unroll
        for (int t = 0; t < 2; ++t)
#pragma unroll
          for (int rr = 0; rr < 4; ++rr) {
            const float mnew = fmaxf(mrow[t][rr], pmv[t][rr]);
            const float corr = __expf(mrow[t][rr] - mnew);
            lrow[t][rr] *= corr;
            mrow[t][rr] = mnew;
#pragma unroll
            for (int jj = 0; jj < 8; ++jj) o[t][jj][rr] *= corr;
          }
      }

      // ---- P = exp(S - m), partial sums, per-wave LDS transpose ----
#pragma unroll
      for (int t = 0; t < 2; ++t)
#pragma unroll
        for (int rr = 0; rr < 4; ++rr) {
          const float p0 = __expf(s_[t][0][rr] - mrow[t][rr]);
          const float p1 = __expf(s_[t][1][rr] - mrow[t][rr]);
          lrow[t][rr] += p0 + p1;
          myP[(t * 16 + q4 + rr) * 40 + fr]      = f2bf(p0);
          myP[(t * 16 + q4 + rr) * 40 + 16 + fr] = f2bf(p1);
        }
      short8 pa[2];
      pa[0] = *(const short8*)&myP[fr * 40 + kk8];
      pa[1] = *(const short8*)&myP[(16 + fr) * 40 + kk8];

      // ---- O += P V ----
#pragma unroll
      for (int jj = 0; jj < 8; ++jj) {
        o[0][jj] = __builtin_amdgcn_mfma_f32_16x16x32_bf16(pa[0], vf[jj], o[0][jj], 0, 0, 0);
        o[1][jj] = __builtin_amdgcn_mfma_f32_16x16x32_bf16(pa[1], vf[jj], o[1][jj], 0, 0, 0);
      }
    }

    // ---- epilogue: reduce l across 16-lane row group, normalize, store ----
#pragma unroll
    for (int t = 0; t < 2; ++t)
#pragma unroll
      for (int rr = 0; rr < 4; ++rr) {
        float rs = lrow[t][rr];
#pragma unroll
        for (int m = 1; m < 16; m <<= 1) rs += __shfl_xor(rs, m);
        const float inv = 1.f / rs;
        const size_t tok = (size_t)b * Sc + qb * 32 + t * 16 + q4 + rr;
#pragma unroll
        for (int jj = 0; jj < 8; ++jj)
          attn[tok * (size_t)(NHc * Dc) + h * Dc + jj * 16 + fr] = f2bf(o[t][jj][rr] * inv);
      }
  };

  process(31 - j);   // heavy member of the pair
  process(j);        // light member -> uniform 33 iters total per wave
}

// ---------------------------------------------------------------------------
extern "C" void kernel_launch(void* const* d_in, const int* in_sizes, int n_in,
                              void* d_out, int out_size, void* d_ws, size_t ws_size,
                              hipStream_t stream)
{
  const float* hidden = (const float*)d_in[0];
  const float* w_qkv  = (const float*)d_in[1];
  const float* w_o    = (const float*)d_in[2];
  float* out = (float*)d_out;

  // workspace layout (bf16 elems): 134.2 MB total
  ushort_t* wqT   = (ushort_t*)d_ws;                   // [6144][4096]  50.3MB
  ushort_t* hidb  = wqT + (size_t)QKVO * Hc;           // [4096][4096]  33.6MB
  ushort_t* qkvb  = hidb + (size_t)Mc * Hc;            // [4096][6144]  50.3MB
  ushort_t* attnb = hidb;                              // reuse after GEMM1
  ushort_t* woT   = wqT;                               // reuse after GEMM1
  ushort_t* vtb   = wqT + (size_t)Mc * Hc;             // reuse: wqT+33.6MB, 8.4MB

  // 1) hidden -> bf16
  cvt_bf16<<<dim3((Mc * Hc / 8) / 256), dim3(256), 0, stream>>>(
      hidden, hidb, Mc * Hc / 8);
  // 2) w_qkv^T -> bf16  [6144][4096]
  transpose_cvt<<<dim3((Hc / 64) * (QKVO / 64)), dim3(256), 0, stream>>>(
      w_qkv, wqT, Hc, QKVO);
  // 3) qkv = hidden @ w_qkv
  gemm_nt<true><<<dim3((Mc / 128) * (QKVO / 128)), dim3(256), 0, stream>>>(
      hidb, wqT, qkvb, Mc, QKVO, Hc);
  // 4) V -> VT  [b][hkv][d][s]
  v_transpose<<<dim3(1024), dim3(256), 0, stream>>>(qkvb, vtb);
  // 5) attention
  attn_fwd<<<dim3(512), dim3(256), 0, stream>>>(qkvb, vtb, attnb);
  // 6) w_o^T -> bf16  [4096][4096]
  transpose_cvt<<<dim3((Hc / 64) * (Hc / 64)), dim3(256), 0, stream>>>(
      w_o, woT, Hc, Hc);
  // 7) out = attn @ w_o
  gemm_nt<false><<<dim3((Mc / 128) * (Hc / 128)), dim3(256), 0, stream>>>(
      attnb, woT, out, Mc, Hc, Hc);
}

// Round 6
// 576.788 us; speedup vs baseline: 2.1334x; 1.1141x over previous
//
#include <hip/hip_runtime.h>
#include <stdint.h>

typedef __attribute__((ext_vector_type(4))) float floatx4;
typedef __attribute__((ext_vector_type(8))) short short8;
typedef unsigned short ushort_t;

#define DEVI __device__ __forceinline__

// Problem constants
constexpr int Bc   = 4;
constexpr int Sc   = 1024;
constexpr int Hc   = 4096;
constexpr int NHc  = 32;
constexpr int NKVc = 8;
constexpr int Dc   = 128;
constexpr int QKVO = 6144;           // NH*D + 2*NKV*D
constexpr int Mc   = Bc * Sc;        // 4096 tokens

DEVI ushort_t f2bf(float f) {
  union { float f; unsigned u; } x; x.f = f;
  unsigned u = x.u;
  u += 0x7fffu + ((u >> 16) & 1u);   // RNE
  return (ushort_t)(u >> 16);
}

DEVI short8 cvt8(floatx4 a, floatx4 b) {
  short8 r;
  r[0] = (short)f2bf(a[0]); r[1] = (short)f2bf(a[1]);
  r[2] = (short)f2bf(a[2]); r[3] = (short)f2bf(a[3]);
  r[4] = (short)f2bf(b[0]); r[5] = (short)f2bf(b[1]);
  r[6] = (short)f2bf(b[2]); r[7] = (short)f2bf(b[3]);
  return r;
}

DEVI void load_lds16(const ushort_t* g, ushort_t* l) {
  __builtin_amdgcn_global_load_lds(
      (const __attribute__((address_space(1))) void*)g,
      (__attribute__((address_space(3))) void*)l, 16, 0, 0);
}

#define BARRIER()  asm volatile("s_barrier" ::: "memory")
#define LGKM0()    asm volatile("s_waitcnt lgkmcnt(0)" ::: "memory")
#define VMCNT(n)   asm volatile("s_waitcnt vmcnt(" #n ")" ::: "memory")

// ---------------------------------------------------------------------------
// f32 -> bf16 plain convert (8 elems/thread)
// ---------------------------------------------------------------------------
__global__ __launch_bounds__(256)
void cvt_bf16(const float* __restrict__ src, ushort_t* __restrict__ dst, int n8)
{
  const int i = blockIdx.x * 256 + threadIdx.x;
  if (i >= n8) return;
  const floatx4 f0 = *(const floatx4*)(src + (size_t)i * 8);
  const floatx4 f1 = *(const floatx4*)(src + (size_t)i * 8 + 4);
  *(short8*)(dst + (size_t)i * 8) = cvt8(f0, f1);
}

// ---------------------------------------------------------------------------
// transpose + convert: src[R][C] f32 -> dst[C][R] bf16.  64x64 tiles.
// ---------------------------------------------------------------------------
__global__ __launch_bounds__(256)
void transpose_cvt(const float* __restrict__ src, ushort_t* __restrict__ dst,
                   int R, int C)
{
  __shared__ float ts[64][67];
  const int cb = C >> 6;
  const int r0 = (blockIdx.x / cb) << 6;
  const int c0 = (blockIdx.x % cb) << 6;
  const int t  = threadIdx.x;

  const int lr = t >> 4, lc = (t & 15) << 2;
#pragma unroll
  for (int i = 0; i < 4; ++i) {
    const floatx4 v = *(const floatx4*)(src + (size_t)(r0 + lr + 16 * i) * C + c0 + lc);
#pragma unroll
    for (int j = 0; j < 4; ++j) ts[lr + 16 * i][lc + j] = v[j];
  }
  __syncthreads();

  const int c     = ((t >> 6) << 4) + ((t & 63) >> 2);
  const int chunk = t & 3;
  short8 t0, t1;
#pragma unroll
  for (int k = 0; k < 8; ++k) t0[k] = (short)f2bf(ts[chunk * 16 + k][c]);
#pragma unroll
  for (int k = 0; k < 8; ++k) t1[k] = (short)f2bf(ts[chunk * 16 + 8 + k][c]);
  ushort_t* dp = dst + (size_t)(c0 + c) * R + r0 + chunk * 16;
  *(short8*)dp       = t0;
  *(short8*)(dp + 8) = t1;
}

// ---------------------------------------------------------------------------
// V transpose (bf16 -> bf16): qkv[b][s][5120 + hkv*128 + d] -> vt[b][hkv][d][s]
// ---------------------------------------------------------------------------
__global__ __launch_bounds__(256)
void v_transpose(const ushort_t* __restrict__ qkv, ushort_t* __restrict__ vt)
{
  __shared__ ushort_t ts[64][72];
  const int bid = blockIdx.x;
  const int db  = bid & 1;
  const int sb  = (bid >> 1) & 15;
  const int hkv = (bid >> 5) & 7;
  const int b   = bid >> 8;
  const int t   = threadIdx.x;

  const ushort_t* src = qkv + (size_t)(b * Sc + sb * 64) * QKVO
                        + (NHc * Dc + NKVc * Dc) + hkv * Dc + db * 64;
  const int lr = t >> 3, lc = (t & 7) * 8;
  *(short8*)&ts[lr][lc]      = *(const short8*)(src + (size_t)lr * QKVO + lc);
  *(short8*)&ts[lr + 32][lc] = *(const short8*)(src + (size_t)(lr + 32) * QKVO + lc);
  __syncthreads();

  ushort_t* dst = vt + ((size_t)(b * NKVc + hkv) * Dc + db * 64) * Sc + sb * 64;
  const int dr  = t >> 2;
  const int sc0 = (t & 3) * 16;
  short8 o0, o1;
#pragma unroll
  for (int k = 0; k < 8; ++k) o0[k] = (short)ts[sc0 + k][dr];
#pragma unroll
  for (int k = 0; k < 8; ++k) o1[k] = (short)ts[sc0 + 8 + k][dr];
  *(short8*)(dst + (size_t)dr * Sc + sc0)     = o0;
  *(short8*)(dst + (size_t)dr * Sc + sc0 + 8) = o1;
}

// ---------------------------------------------------------------------------
// 256x256 8-phase GEMM: C[M,N] = A[M,K] * BT[N,K]^T, bf16 in, f32/bf16 out.
// 512 thr = 8 waves (2M x 4N); wave owns 128x64.  BK=64, dbuf LDS 128KB.
// XOR swizzle (storage_byte = logical ^ ((row&7)<<4)), linear gload_lds dest +
// inverse-swizzled global source.  Counted vmcnt: stage order per wave per
// K-tile = [A x4 (ph0,ph1), Bev x2 (ph2), Bod x2 (ph3)], staged 1 group ahead;
// vmcnt(4) end-ph1 forces prev Bod (read ph2); vmcnt(2) end-ph3 forces A+Bev
// (read next ph0/ph1).  Quadrants: M03xNev, M47xNev, M47xNod, M03xNod.
// ---------------------------------------------------------------------------
template<bool OBF16>
__global__ __launch_bounds__(512, 2)
void gemm_nt8(const ushort_t* __restrict__ A, const ushort_t* __restrict__ BT,
              void* __restrict__ Cp, int M, int N, int K)
{
  __shared__ __align__(16) ushort_t As[2][256 * 64];
  __shared__ __align__(16) ushort_t Bs[2][256 * 64];

  const int nb  = N >> 8;
  const int nwg = (M >> 8) * nb;
  int bid = blockIdx.x;
  bid = (bid & 7) * (nwg >> 3) + (bid >> 3);     // XCD swizzle (nwg%8==0)
  const int bm = bid / nb, bn = bid % nb;
  const int m0 = bm << 8, n0 = bn << 8;

  const int tid  = threadIdx.x;
  const int wid  = tid >> 6, lane = tid & 63;
  const int wm   = wid >> 2, wn = wid & 3;       // wave grid 2x4
  const int fr   = lane & 15;
  const int g16  = (lane >> 4) << 4;             // frag k byte base
  const int rsw  = (fr & 7) << 4;                // read-side XOR
  const int l8   = lane >> 3;
  const int scol = ((lane & 7) ^ l8) << 3;       // pre-swizzled src col (ushorts)

  const int arow0 = wm * 128 + wn * 32;                    // A stager rows
  const int brow0 = (((wn >> 1) << 3) + ((wm * 2 + (wn & 1)) << 1)) * 16; // fe*16

  const ushort_t* agl = A  + (size_t)(m0 + arow0 + l8) * K + scol;
  const ushort_t* bgl = BT + (size_t)(n0 + brow0 + l8) * K + scol;

  const int rowA = (wm * 128 + fr) * 128;        // byte base for A frag reads
  const int rowB = (wn * 64 + fr) * 128;
  const int cb0  = g16 ^ rsw;
  const int cb1  = (64 + g16) ^ rsw;

  const floatx4 fz = {0.f, 0.f, 0.f, 0.f};
  floatx4 acc[8][4];
#pragma unroll
  for (int i = 0; i < 8; ++i)
#pragma unroll
    for (int f = 0; f < 4; ++f) acc[i][f] = fz;

  // ---- prologue: stage tile 0 into buf 0, drain ----
  load_lds16(agl,                  &As[0][(arow0 +  0) * 64]);
  load_lds16(agl +  8 * (size_t)K, &As[0][(arow0 +  8) * 64]);
  load_lds16(agl + 16 * (size_t)K, &As[0][(arow0 + 16) * 64]);
  load_lds16(agl + 24 * (size_t)K, &As[0][(arow0 + 24) * 64]);
  load_lds16(bgl,                  &Bs[0][(brow0 +  0) * 64]);
  load_lds16(bgl +  8 * (size_t)K, &Bs[0][(brow0 +  8) * 64]);
  load_lds16(bgl + 16 * (size_t)K, &Bs[0][(brow0 + 16) * 64]);
  load_lds16(bgl + 24 * (size_t)K, &Bs[0][(brow0 + 24) * 64]);
  VMCNT(0);
  BARRIER();

  const int NT = K >> 6;
  for (int kt = 0; kt < NT; ++kt) {
    const int u = kt & 1, v = u ^ 1;
    const char* Au = (const char*)&As[u][0];
    const char* Bu = (const char*)&Bs[u][0];
    const bool st  = (kt + 1 < NT);
    const size_t kn = (size_t)(kt + 1) << 6;

#define LDA(i, ks) (*(const short8*)(Au + rowA + (i) * 2048 + ((ks) ? cb1 : cb0)))
#define LDB(f, ks) (*(const short8*)(Bu + rowB + (f) * 2048 + ((ks) ? cb1 : cb0)))
#define MFMA16(d, a0, a1, b0, b1)                                         \
    d = __builtin_amdgcn_mfma_f32_16x16x32_bf16(a0, b0, d, 0, 0, 0);      \
    d = __builtin_amdgcn_mfma_f32_16x16x32_bf16(a1, b1, d, 0, 0, 0);

    short8 aR[4][2], bE[2][2], bO[2][2];

    // ---------------- phase 0: M0-3 x {N0,N2} ----------------
#pragma unroll
    for (int i = 0; i < 4; ++i) { aR[i][0] = LDA(i, 0); aR[i][1] = LDA(i, 1); }
#pragma unroll
    for (int f = 0; f < 2; ++f) { bE[f][0] = LDB(2 * f, 0); bE[f][1] = LDB(2 * f, 1); }
    if (st) {
      load_lds16(agl + kn,                 &As[v][(arow0 + 0) * 64]);
      load_lds16(agl + 8 * (size_t)K + kn, &As[v][(arow0 + 8) * 64]);
    }
    BARRIER();
    __builtin_amdgcn_s_setprio(1);
#pragma unroll
    for (int i = 0; i < 4; ++i)
#pragma unroll
      for (int f = 0; f < 2; ++f) { MFMA16(acc[i][2 * f], aR[i][0], aR[i][1], bE[f][0], bE[f][1]); }
    __builtin_amdgcn_s_setprio(0);
    LGKM0();
    BARRIER();

    // ---------------- phase 1: M4-7 x {N0,N2} ----------------
#pragma unroll
    for (int i = 0; i < 4; ++i) { aR[i][0] = LDA(4 + i, 0); aR[i][1] = LDA(4 + i, 1); }
    if (st) {
      load_lds16(agl + 16 * (size_t)K + kn, &As[v][(arow0 + 16) * 64]);
      load_lds16(agl + 24 * (size_t)K + kn, &As[v][(arow0 + 24) * 64]);
    }
    BARRIER();
    __builtin_amdgcn_s_setprio(1);
#pragma unroll
    for (int i = 0; i < 4; ++i)
#pragma unroll
      for (int f = 0; f < 2; ++f) { MFMA16(acc[4 + i][2 * f], aR[i][0], aR[i][1], bE[f][0], bE[f][1]); }
    __builtin_amdgcn_s_setprio(0);
    LGKM0();
    if (st) { VMCNT(4); } else { VMCNT(0); }   // force prev group's B-odd
    BARRIER();

    // ---------------- phase 2: M4-7 x {N1,N3} ----------------
#pragma unroll
    for (int f = 0; f < 2; ++f) { bO[f][0] = LDB(2 * f + 1, 0); bO[f][1] = LDB(2 * f + 1, 1); }
    if (st) {
      load_lds16(bgl + kn,                 &Bs[v][(brow0 + 0) * 64]);
      load_lds16(bgl + 8 * (size_t)K + kn, &Bs[v][(brow0 + 8) * 64]);
    }
    BARRIER();
    __builtin_amdgcn_s_setprio(1);
#pragma unroll
    for (int i = 0; i < 4; ++i)
#pragma unroll
      for (int f = 0; f < 2; ++f) { MFMA16(acc[4 + i][2 * f + 1], aR[i][0], aR[i][1], bO[f][0], bO[f][1]); }
    __builtin_amdgcn_s_setprio(0);
    LGKM0();
    BARRIER();

    // ---------------- phase 3: M0-3 x {N1,N3} ----------------
#pragma unroll
    for (int i = 0; i < 4; ++i) { aR[i][0] = LDA(i, 0); aR[i][1] = LDA(i, 1); }
    if (st) {
      load_lds16(bgl + 16 * (size_t)K + kn, &Bs[v][(brow0 + 16) * 64]);
      load_lds16(bgl + 24 * (size_t)K + kn, &Bs[v][(brow0 + 24) * 64]);
    }
    BARRIER();
    __builtin_amdgcn_s_setprio(1);
#pragma unroll
    for (int i = 0; i < 4; ++i)
#pragma unroll
      for (int f = 0; f < 2; ++f) { MFMA16(acc[i][2 * f + 1], aR[i][0], aR[i][1], bO[f][0], bO[f][1]); }
    __builtin_amdgcn_s_setprio(0);
    LGKM0();
    VMCNT(2);                                   // force next tile's A + B-even
    BARRIER();

#undef LDA
#undef LDB
#undef MFMA16
  }

  // ---- epilogue ----
  const int r4 = (lane >> 4) << 2;
#pragma unroll
  for (int i = 0; i < 8; ++i) {
#pragma unroll
    for (int rr = 0; rr < 4; ++rr) {
      const size_t row = (size_t)(m0 + wm * 128 + i * 16 + r4 + rr);
#pragma unroll
      for (int f = 0; f < 4; ++f) {
        const size_t col = (size_t)(n0 + wn * 64 + f * 16 + fr);
        if constexpr (OBF16)
          ((ushort_t*)Cp)[row * N + col] = f2bf(acc[i][f][rr]);
        else
          ((float*)Cp)[row * N + col] = acc[i][f][rr];
      }
    }
  }
}

// ---------------------------------------------------------------------------
// Flash attention, causal + ALiBi-sqrt (unchanged from R4).
// ---------------------------------------------------------------------------
__global__ __launch_bounds__(256, 2)
void attn_fwd(const ushort_t* __restrict__ qkv,
              const ushort_t* __restrict__ vt,
              ushort_t* __restrict__ attn)
{
  __shared__ __align__(16) ushort_t Plds[4][32 * 40];

  const int bid = blockIdx.x;          // 512 blocks
  const int x   = bid & 7;
  const int p   = bid >> 3;
  const int j   = p & 15;
  const int g   = ((p >> 4) << 3) + x;
  const int b   = g >> 3;
  const int hkv = g & 7;

  const int tid  = threadIdx.x;
  const int wid  = tid >> 6, lane = tid & 63;
  const int h    = hkv * 4 + wid;
  const int fr   = lane & 15;
  const int kk8  = (lane >> 4) << 3;
  const int q4   = (lane >> 4) << 2;
  const float slope = exp2f(-0.25f * (float)(h + 1));
  const float scale = 0.08838834764831845f;

  const ushort_t* qp  = qkv + (size_t)b * Sc * QKVO + (size_t)h * Dc;
  const ushort_t* kp  = qkv + (size_t)b * Sc * QKVO + NHc * Dc + (size_t)hkv * Dc;
  const ushort_t* vtp = vt + (size_t)(b * NKVc + hkv) * Dc * Sc;
  ushort_t* myP = &Plds[wid][0];

  const floatx4 fz = {0.f, 0.f, 0.f, 0.f};

  auto process = [&](const int qb) {
    short8 qf[2][4];
#pragma unroll
    for (int t = 0; t < 2; ++t) {
      const int qrow = qb * 32 + t * 16 + fr;
#pragma unroll
      for (int s = 0; s < 4; ++s)
        qf[t][s] = *(const short8*)(qp + (size_t)qrow * QKVO + s * 32 + kk8);
    }

    floatx4 o[2][8];
#pragma unroll
    for (int t = 0; t < 2; ++t)
#pragma unroll
      for (int jj = 0; jj < 8; ++jj) o[t][jj] = fz;
    float mrow[2][4], lrow[2][4];
#pragma unroll
    for (int t = 0; t < 2; ++t)
#pragma unroll
      for (int rr = 0; rr < 4; ++rr) { mrow[t][rr] = -1e30f; lrow[t][rr] = 0.f; }

    for (int kb = 0; kb <= qb; ++kb) {
      floatx4 s_[2][2];
      s_[0][0] = fz; s_[0][1] = fz; s_[1][0] = fz; s_[1][1] = fz;
#pragma unroll
      for (int half = 0; half < 2; ++half) {
        const int kcol = kb * 32 + half * 16 + fr;
#pragma unroll
        for (int s = 0; s < 4; ++s) {
          const short8 kf = *(const short8*)(kp + (size_t)kcol * QKVO + s * 32 + kk8);
          s_[0][half] = __builtin_amdgcn_mfma_f32_16x16x32_bf16(qf[0][s], kf, s_[0][half], 0, 0, 0);
          s_[1][half] = __builtin_amdgcn_mfma_f32_16x16x32_bf16(qf[1][s], kf, s_[1][half], 0, 0, 0);
        }
      }

      short8 vf[8];
#pragma unroll
      for (int jj = 0; jj < 8; ++jj)
        vf[jj] = *(const short8*)(vtp + (size_t)(jj * 16 + fr) * Sc + kb * 32 + kk8);

#pragma unroll
      for (int t = 0; t < 2; ++t)
#pragma unroll
        for (int rr = 0; rr < 4; ++rr) {
          const int qg  = qb * 32 + t * 16 + q4 + rr;
          const int dk0 = qg - (kb * 32 + fr);
          const int dk1 = dk0 - 16;
          s_[t][0][rr] = (dk0 >= 0)
              ? s_[t][0][rr] * scale - slope * sqrtf((float)dk0) : -1e30f;
          s_[t][1][rr] = (dk1 >= 0)
              ? s_[t][1][rr] * scale - slope * sqrtf((float)dk1) : -1e30f;
        }

      float pmv[2][4];
#pragma unroll
      for (int t = 0; t < 2; ++t)
#pragma unroll
        for (int rr = 0; rr < 4; ++rr) {
          float pm = fmaxf(s_[t][0][rr], s_[t][1][rr]);
#pragma unroll
          for (int m = 1; m < 16; m <<= 1) pm = fmaxf(pm, __shfl_xor(pm, m));
          pmv[t][rr] = pm;
        }

      int need = 0;
#pragma unroll
      for (int t = 0; t < 2; ++t)
#pragma unroll
        for (int rr = 0; rr < 4; ++rr)
          need |= (pmv[t][rr] > mrow[t][rr] + 8.f) ? 1 : 0;
      if (__any(need)) {
#pragma unroll
        for (int t = 0; t < 2; ++t)
#pragma unroll
          for (int rr = 0; rr < 4; ++rr) {
            const float mnew = fmaxf(mrow[t][rr], pmv[t][rr]);
            const float corr = __expf(mrow[t][rr] - mnew);
            lrow[t][rr] *= corr;
            mrow[t][rr] = mnew;
#pragma unroll
            for (int jj = 0; jj < 8; ++jj) o[t][jj][rr] *= corr;
          }
      }

#pragma unroll
      for (int t = 0; t < 2; ++t)
#pragma unroll
        for (int rr = 0; rr < 4; ++rr) {
          const float p0 = __expf(s_[t][0][rr] - mrow[t][rr]);
          const float p1 = __expf(s_[t][1][rr] - mrow[t][rr]);
          lrow[t][rr] += p0 + p1;
          myP[(t * 16 + q4 + rr) * 40 + fr]      = f2bf(p0);
          myP[(t * 16 + q4 + rr) * 40 + 16 + fr] = f2bf(p1);
        }
      short8 pa[2];
      pa[0] = *(const short8*)&myP[fr * 40 + kk8];
      pa[1] = *(const short8*)&myP[(16 + fr) * 40 + kk8];

#pragma unroll
      for (int jj = 0; jj < 8; ++jj) {
        o[0][jj] = __builtin_amdgcn_mfma_f32_16x16x32_bf16(pa[0], vf[jj], o[0][jj], 0, 0, 0);
        o[1][jj] = __builtin_amdgcn_mfma_f32_16x16x32_bf16(pa[1], vf[jj], o[1][jj], 0, 0, 0);
      }
    }

#pragma unroll
    for (int t = 0; t < 2; ++t)
#pragma unroll
      for (int rr = 0; rr < 4; ++rr) {
        float rs = lrow[t][rr];
#pragma unroll
        for (int m = 1; m < 16; m <<= 1) rs += __shfl_xor(rs, m);
        const float inv = 1.f / rs;
        const size_t tok = (size_t)b * Sc + qb * 32 + t * 16 + q4 + rr;
#pragma unroll
        for (int jj = 0; jj < 8; ++jj)
          attn[tok * (size_t)(NHc * Dc) + h * Dc + jj * 16 + fr] = f2bf(o[t][jj][rr] * inv);
      }
  };

  process(31 - j);
  process(j);
}

// ---------------------------------------------------------------------------
extern "C" void kernel_launch(void* const* d_in, const int* in_sizes, int n_in,
                              void* d_out, int out_size, void* d_ws, size_t ws_size,
                              hipStream_t stream)
{
  const float* hidden = (const float*)d_in[0];
  const float* w_qkv  = (const float*)d_in[1];
  const float* w_o    = (const float*)d_in[2];
  float* out = (float*)d_out;

  // workspace layout (bf16 elems): 134.2 MB total
  ushort_t* wqT   = (ushort_t*)d_ws;                   // [6144][4096]  50.3MB
  ushort_t* hidb  = wqT + (size_t)QKVO * Hc;           // [4096][4096]  33.6MB
  ushort_t* qkvb  = hidb + (size_t)Mc * Hc;            // [4096][6144]  50.3MB
  ushort_t* attnb = hidb;                              // reuse after GEMM1
  ushort_t* woT   = wqT;                               // reuse after GEMM1
  ushort_t* vtb   = wqT + (size_t)Mc * Hc;             // reuse: wqT+33.6MB, 8.4MB

  // 1) hidden -> bf16
  cvt_bf16<<<dim3((Mc * Hc / 8) / 256), dim3(256), 0, stream>>>(
      hidden, hidb, Mc * Hc / 8);
  // 2) w_qkv^T -> bf16  [6144][4096]
  transpose_cvt<<<dim3((Hc / 64) * (QKVO / 64)), dim3(256), 0, stream>>>(
      w_qkv, wqT, Hc, QKVO);
  // 3) qkv = hidden @ w_qkv
  gemm_nt8<true><<<dim3((Mc / 256) * (QKVO / 256)), dim3(512), 0, stream>>>(
      hidb, wqT, qkvb, Mc, QKVO, Hc);
  // 4) V -> VT  [b][hkv][d][s]
  v_transpose<<<dim3(1024), dim3(256), 0, stream>>>(qkvb, vtb);
  // 5) attention
  attn_fwd<<<dim3(512), dim3(256), 0, stream>>>(qkvb, vtb, attnb);
  // 6) w_o^T -> bf16  [4096][4096]
  transpose_cvt<<<dim3((Hc / 64) * (Hc / 64)), dim3(256), 0, stream>>>(
      w_o, woT, Hc, Hc);
  // 7) out = attn @ w_o
  gemm_nt8<false><<<dim3((Mc / 256) * (Hc / 256)), dim3(512), 0, stream>>>(
      attnb, woT, out, Mc, Hc, Hc);
}